// Round 1
// baseline (2110.237 us; speedup 1.0000x reference)
//
#include <hip/hip_runtime.h>

#define N_NODES 50000
#define N_EDGES 800000
#define N_GRAPHS 64
#define F 256        // F_IN == F_HID
#define F_OUT 128
#define G_DIM 768    // 3*F

// ---------------- degree / norm ----------------
__global__ void init_deg(float* deg) {
    int i = blockIdx.x * blockDim.x + threadIdx.x;
    if (i < N_NODES) deg[i] = 1.0f;   // self-loop counts 1
}

__global__ void accum_deg(const int* __restrict__ dst, float* deg) {
    int e = blockIdx.x * blockDim.x + threadIdx.x;
    if (e < N_EDGES) atomicAdd(&deg[dst[e]], 1.0f);
}

__global__ void compute_dinv(const float* __restrict__ deg, float* dinv) {
    int i = blockIdx.x * blockDim.x + threadIdx.x;
    if (i < N_NODES) dinv[i] = rsqrtf(deg[i]);   // deg >= 1 always
}

// ---------------- fp32 tiled GEMM: C[M,256] = A[M,256] @ B[256,256] ----------------
#define TM 64
#define TN 64
#define TK 16
__global__ void gemm_fp32(const float* __restrict__ A, const float* __restrict__ B,
                          float* __restrict__ C, int M) {
    __shared__ float As[TK][TM + 1];
    __shared__ float Bs[TK][TN + 1];
    int tx = threadIdx.x % 16, ty = threadIdx.x / 16;
    int row0 = blockIdx.y * TM, col0 = blockIdx.x * TN;
    float acc[4][4] = {};
    for (int kt = 0; kt < 256; kt += TK) {
        for (int i = threadIdx.x; i < TM * TK; i += 256) {
            int r = i / TK, c = i % TK;
            int gr = row0 + r;
            As[c][r] = (gr < M) ? A[(size_t)gr * 256 + kt + c] : 0.0f;
        }
        for (int i = threadIdx.x; i < TK * TN; i += 256) {
            int r = i / TN, c = i % TN;
            Bs[r][c] = B[(size_t)(kt + r) * 256 + col0 + c];
        }
        __syncthreads();
#pragma unroll
        for (int k = 0; k < TK; ++k) {
            float a[4], b[4];
#pragma unroll
            for (int i = 0; i < 4; ++i) a[i] = As[k][ty * 4 + i];
#pragma unroll
            for (int j = 0; j < 4; ++j) b[j] = Bs[k][tx * 4 + j];
#pragma unroll
            for (int i = 0; i < 4; ++i)
#pragma unroll
                for (int j = 0; j < 4; ++j) acc[i][j] += a[i] * b[j];
        }
        __syncthreads();
    }
    for (int i = 0; i < 4; ++i) {
        int gr = row0 + ty * 4 + i;
        if (gr < M) {
            for (int j = 0; j < 4; ++j)
                C[(size_t)gr * 256 + col0 + tx * 4 + j] = acc[i][j];
        }
    }
}

// ---------------- edge scatter: agg[dst] += h[src] * dinv[src]*dinv[dst] ----------------
__global__ void scatter_edges(const int* __restrict__ src, const int* __restrict__ dst,
                              const float* __restrict__ dinv,
                              const float* __restrict__ h, float* agg) {
    int e = blockIdx.x;
    int f = threadIdx.x;
    int s = src[e], d = dst[e];
    float w = dinv[s] * dinv[d];
    atomicAdd(&agg[(size_t)d * F + f], h[(size_t)s * F + f] * w);
}

// ---------------- self-loop + bias + relu (in place on agg) ----------------
__global__ void bias_relu_self(float* agg, const float* __restrict__ hW,
                               const float* __restrict__ dinv, const float* __restrict__ b) {
    int i = blockIdx.x * blockDim.x + threadIdx.x;
    if (i < N_NODES * F) {
        int node = i / F, f = i % F;
        float di = dinv[node];
        float v = agg[i] + hW[i] * di * di + b[f];
        agg[i] = fmaxf(v, 0.0f);
    }
}

// ---------------- triple pooling (batch is sorted) ----------------
__global__ void pool_kernel(const float* __restrict__ h, const int* __restrict__ batch,
                            float* __restrict__ pooled /* [64][768] = mean|max|sum */) {
    int g = blockIdx.x;
    int f = threadIdx.x;  // 256
    __shared__ int s_start, s_end;
    if (threadIdx.x == 0) {
        int lo = 0, hi = N_NODES;
        while (lo < hi) { int mid = (lo + hi) >> 1; if (batch[mid] < g) lo = mid + 1; else hi = mid; }
        s_start = lo;
        lo = 0; hi = N_NODES;
        while (lo < hi) { int mid = (lo + hi) >> 1; if (batch[mid] < g + 1) lo = mid + 1; else hi = mid; }
        s_end = lo;
    }
    __syncthreads();
    int start = s_start, end = s_end;
    float sum = 0.0f, mx = -INFINITY;
    for (int n = start; n < end; ++n) {
        float v = h[(size_t)n * F + f];
        sum += v;
        mx = fmaxf(mx, v);
    }
    int cnt = end - start;
    float mean = sum / fmaxf((float)cnt, 1.0f);
    if (cnt == 0) mx = 0.0f;  // isfinite guard for empty segment
    pooled[g * G_DIM + f]           = mean;
    pooled[g * G_DIM + 256 + f]     = mx;
    pooled[g * G_DIM + 512 + f]     = sum;
}

// ---------------- final GEMM: out[64,128] = pooled[64,768] @ Wfc[768,128] + bfc ----------------
__global__ void final_gemm(const float* __restrict__ pooled, const float* __restrict__ Wfc,
                           const float* __restrict__ bfc, float* __restrict__ out) {
    int g = blockIdx.x;   // 64
    int o = threadIdx.x;  // 128
    __shared__ float row[G_DIM];
    for (int i = threadIdx.x; i < G_DIM; i += 128) row[i] = pooled[g * G_DIM + i];
    __syncthreads();
    float acc = bfc[o];
    for (int k = 0; k < G_DIM; ++k) acc += row[k] * Wfc[k * F_OUT + o];
    out[g * F_OUT + o] = acc;
}

extern "C" void kernel_launch(void* const* d_in, const int* in_sizes, int n_in,
                              void* d_out, int out_size, void* d_ws, size_t ws_size,
                              hipStream_t stream) {
    const float* x    = (const float*)d_in[0];
    const int*   ei   = (const int*)d_in[1];   // [2, N_EDGES]: row0 = src, row1 = dst
    const int*   batch= (const int*)d_in[2];
    // d_in[3] = n_graphs scalar (=64), hardcoded
    const float* W1   = (const float*)d_in[4];
    const float* b1   = (const float*)d_in[5];
    const float* W2   = (const float*)d_in[6];
    const float* b2   = (const float*)d_in[7];
    const float* Wfc  = (const float*)d_in[8];
    const float* bfc  = (const float*)d_in[9];
    float* out = (float*)d_out;

    const int* src = ei;
    const int* dst = ei + N_EDGES;

    float* bufA   = (float*)d_ws;                       // [N_NODES, F] transformed h
    float* bufB   = bufA + (size_t)N_NODES * F;         // [N_NODES, F] aggregation / h
    float* deg    = bufB + (size_t)N_NODES * F;
    float* dinv   = deg + N_NODES;
    float* pooled = dinv + N_NODES;                     // [64, 768]

    // ---- normalization ----
    init_deg<<<(N_NODES + 255) / 256, 256, 0, stream>>>(deg);
    accum_deg<<<(N_EDGES + 255) / 256, 256, 0, stream>>>(dst, deg);
    compute_dinv<<<(N_NODES + 255) / 256, 256, 0, stream>>>(deg, dinv);

    dim3 ggrid(F / TN, (N_NODES + TM - 1) / TM);

    // ---- layer 1 ----
    gemm_fp32<<<ggrid, 256, 0, stream>>>(x, W1, bufA, N_NODES);
    hipMemsetAsync(bufB, 0, (size_t)N_NODES * F * sizeof(float), stream);
    scatter_edges<<<N_EDGES, 256, 0, stream>>>(src, dst, dinv, bufA, bufB);
    bias_relu_self<<<(N_NODES * F + 255) / 256, 256, 0, stream>>>(bufB, bufA, dinv, b1);

    // ---- layer 2 ----
    gemm_fp32<<<ggrid, 256, 0, stream>>>(bufB, W2, bufA, N_NODES);
    hipMemsetAsync(bufB, 0, (size_t)N_NODES * F * sizeof(float), stream);
    scatter_edges<<<N_EDGES, 256, 0, stream>>>(src, dst, dinv, bufA, bufB);
    bias_relu_self<<<(N_NODES * F + 255) / 256, 256, 0, stream>>>(bufB, bufA, dinv, b2);

    // ---- pooling + classifier ----
    pool_kernel<<<N_GRAPHS, 256, 0, stream>>>(bufB, batch, pooled);
    final_gemm<<<N_GRAPHS, F_OUT, 0, stream>>>(pooled, Wfc, bfc, out);
}

// Round 2
// 1008.695 us; speedup vs baseline: 2.0920x; 2.0920x over previous
//
#include <hip/hip_runtime.h>

#define N_NODES 50000
#define N_EDGES 800000
#define N_GRAPHS 64
#define F 256        // F_IN == F_HID
#define F_OUT 128
#define G_DIM 768    // 3*F
#define SCAN_NB ((N_NODES + 255) / 256)   // 196

// ---------------- degree count (int) ----------------
__global__ void count_deg(const int* __restrict__ dst, int* deg) {
    int e = blockIdx.x * blockDim.x + threadIdx.x;
    if (e < N_EDGES) atomicAdd(&deg[dst[e]], 1);
}

__global__ void compute_dinv(const int* __restrict__ deg, float* dinv) {
    int i = blockIdx.x * blockDim.x + threadIdx.x;
    if (i < N_NODES) dinv[i] = rsqrtf((float)(deg[i] + 1));   // +1 self-loop
}

// ---------------- 3-kernel exclusive scan over deg -> row_ptr ----------------
__global__ void scan_blocks(const int* __restrict__ deg, int* __restrict__ row_ptr,
                            int* __restrict__ block_tot) {
    __shared__ int sd[256];
    int t = threadIdx.x;
    int idx = blockIdx.x * 256 + t;
    int v = (idx < N_NODES) ? deg[idx] : 0;
    sd[t] = v;
    __syncthreads();
    for (int off = 1; off < 256; off <<= 1) {
        int a = (t >= off) ? sd[t - off] : 0;
        __syncthreads();
        sd[t] += a;
        __syncthreads();
    }
    if (idx < N_NODES) row_ptr[idx] = sd[t] - v;   // block-local exclusive
    if (t == 255) block_tot[blockIdx.x] = sd[255];
}

__global__ void scan_totals(int* block_tot) {
    __shared__ int sd[256];
    int t = threadIdx.x;
    int v = (t < SCAN_NB) ? block_tot[t] : 0;
    sd[t] = v;
    __syncthreads();
    for (int off = 1; off < 256; off <<= 1) {
        int a = (t >= off) ? sd[t - off] : 0;
        __syncthreads();
        sd[t] += a;
        __syncthreads();
    }
    if (t < SCAN_NB) block_tot[t] = sd[t] - v;     // exclusive block offsets
}

__global__ void add_offsets(int* __restrict__ row_ptr, const int* __restrict__ block_tot) {
    int idx = blockIdx.x * 256 + threadIdx.x;
    if (idx < N_NODES) row_ptr[idx] += block_tot[blockIdx.x];
    if (idx == 0) row_ptr[N_NODES] = N_EDGES;
}

// ---------------- bucket edges into CSR order ----------------
__global__ void bucket_edges(const int* __restrict__ src, const int* __restrict__ dst,
                             const int* __restrict__ row_ptr, int* __restrict__ cursor,
                             int* __restrict__ srcs_sorted) {
    int e = blockIdx.x * blockDim.x + threadIdx.x;
    if (e < N_EDGES) {
        int d = dst[e];
        int pos = atomicAdd(&cursor[d], 1);
        srcs_sorted[row_ptr[d] + pos] = src[e];
    }
}

// ---------------- fp32 tiled GEMM: C[M,256] = A[M,256] @ B[256,256] ----------------
#define TM 64
#define TN 64
#define TK 16
__global__ void gemm_fp32(const float* __restrict__ A, const float* __restrict__ B,
                          float* __restrict__ C, int M) {
    __shared__ float As[TK][TM + 1];
    __shared__ float Bs[TK][TN + 1];
    int tx = threadIdx.x % 16, ty = threadIdx.x / 16;
    int row0 = blockIdx.y * TM, col0 = blockIdx.x * TN;
    float acc[4][4] = {};
    for (int kt = 0; kt < 256; kt += TK) {
        for (int i = threadIdx.x; i < TM * TK; i += 256) {
            int r = i / TK, c = i % TK;
            int gr = row0 + r;
            As[c][r] = (gr < M) ? A[(size_t)gr * 256 + kt + c] : 0.0f;
        }
        for (int i = threadIdx.x; i < TK * TN; i += 256) {
            int r = i / TN, c = i % TN;
            Bs[r][c] = B[(size_t)(kt + r) * 256 + col0 + c];
        }
        __syncthreads();
#pragma unroll
        for (int k = 0; k < TK; ++k) {
            float a[4], b[4];
#pragma unroll
            for (int i = 0; i < 4; ++i) a[i] = As[k][ty * 4 + i];
#pragma unroll
            for (int j = 0; j < 4; ++j) b[j] = Bs[k][tx * 4 + j];
#pragma unroll
            for (int i = 0; i < 4; ++i)
#pragma unroll
                for (int j = 0; j < 4; ++j) acc[i][j] += a[i] * b[j];
        }
        __syncthreads();
    }
    for (int i = 0; i < 4; ++i) {
        int gr = row0 + ty * 4 + i;
        if (gr < M) {
            for (int j = 0; j < 4; ++j)
                C[(size_t)gr * 256 + col0 + tx * 4 + j] = acc[i][j];
        }
    }
}

// -------- CSR gather-aggregate, fused self-loop + bias + relu --------
// one wave per dst node; lane handles 4 contiguous feats (float4)
__global__ __launch_bounds__(64) void gather_agg(
        const int* __restrict__ row_ptr, const int* __restrict__ srcs,
        const float* __restrict__ dinv, const float* __restrict__ hW,
        const float* __restrict__ b, float* __restrict__ out) {
    int node = blockIdx.x;
    int lane = threadIdx.x;   // 64
    int beg = row_ptr[node], end = row_ptr[node + 1];
    float dd = dinv[node];
    const float4* hv = (const float4*)hW;
    float4 acc = make_float4(0.f, 0.f, 0.f, 0.f);
    for (int cbeg = beg; cbeg < end; cbeg += 64) {
        int n = end - cbeg; if (n > 64) n = 64;
        int sv = (lane < n) ? srcs[cbeg + lane] : 0;
        float wv = (lane < n) ? dinv[sv] : 0.f;
        for (int i = 0; i < n; ++i) {
            int s = __shfl(sv, i);
            float w = __shfl(wv, i) * dd;
            float4 v = hv[(size_t)s * 64 + lane];
            acc.x = fmaf(v.x, w, acc.x);
            acc.y = fmaf(v.y, w, acc.y);
            acc.z = fmaf(v.z, w, acc.z);
            acc.w = fmaf(v.w, w, acc.w);
        }
    }
    // self-loop + bias + relu
    float4 sv4 = hv[(size_t)node * 64 + lane];
    float wself = dd * dd;
    float4 b4 = ((const float4*)b)[lane];
    acc.x = fmaxf(fmaf(sv4.x, wself, acc.x) + b4.x, 0.f);
    acc.y = fmaxf(fmaf(sv4.y, wself, acc.y) + b4.y, 0.f);
    acc.z = fmaxf(fmaf(sv4.z, wself, acc.z) + b4.z, 0.f);
    acc.w = fmaxf(fmaf(sv4.w, wself, acc.w) + b4.w, 0.f);
    ((float4*)out)[(size_t)node * 64 + lane] = acc;
}

// ---------------- triple pooling (batch is sorted) ----------------
__global__ void pool_kernel(const float* __restrict__ h, const int* __restrict__ batch,
                            float* __restrict__ pooled /* [64][768] = mean|max|sum */) {
    int g = blockIdx.x;
    int f = threadIdx.x;  // 256
    __shared__ int s_start, s_end;
    if (threadIdx.x == 0) {
        int lo = 0, hi = N_NODES;
        while (lo < hi) { int mid = (lo + hi) >> 1; if (batch[mid] < g) lo = mid + 1; else hi = mid; }
        s_start = lo;
        lo = 0; hi = N_NODES;
        while (lo < hi) { int mid = (lo + hi) >> 1; if (batch[mid] < g + 1) lo = mid + 1; else hi = mid; }
        s_end = lo;
    }
    __syncthreads();
    int start = s_start, end = s_end;
    float sum = 0.0f, mx = -INFINITY;
    for (int n = start; n < end; ++n) {
        float v = h[(size_t)n * F + f];
        sum += v;
        mx = fmaxf(mx, v);
    }
    int cnt = end - start;
    float mean = sum / fmaxf((float)cnt, 1.0f);
    if (cnt == 0) mx = 0.0f;  // isfinite guard for empty segment
    pooled[g * G_DIM + f]           = mean;
    pooled[g * G_DIM + 256 + f]     = mx;
    pooled[g * G_DIM + 512 + f]     = sum;
}

// ---------------- final GEMM: out[64,128] = pooled[64,768] @ Wfc[768,128] + bfc ----------------
__global__ void final_gemm(const float* __restrict__ pooled, const float* __restrict__ Wfc,
                           const float* __restrict__ bfc, float* __restrict__ out) {
    int g = blockIdx.x;   // 64
    int o = threadIdx.x;  // 128
    __shared__ float row[G_DIM];
    for (int i = threadIdx.x; i < G_DIM; i += 128) row[i] = pooled[g * G_DIM + i];
    __syncthreads();
    float acc = bfc[o];
    for (int k = 0; k < G_DIM; ++k) acc += row[k] * Wfc[k * F_OUT + o];
    out[g * F_OUT + o] = acc;
}

extern "C" void kernel_launch(void* const* d_in, const int* in_sizes, int n_in,
                              void* d_out, int out_size, void* d_ws, size_t ws_size,
                              hipStream_t stream) {
    const float* x    = (const float*)d_in[0];
    const int*   ei   = (const int*)d_in[1];   // [2, N_EDGES]: row0 = src, row1 = dst
    const int*   batch= (const int*)d_in[2];
    const float* W1   = (const float*)d_in[4];
    const float* b1   = (const float*)d_in[5];
    const float* W2   = (const float*)d_in[6];
    const float* b2   = (const float*)d_in[7];
    const float* Wfc  = (const float*)d_in[8];
    const float* bfc  = (const float*)d_in[9];
    float* out = (float*)d_out;

    const int* src = ei;
    const int* dst = ei + N_EDGES;

    float* bufA   = (float*)d_ws;                       // [N_NODES, F]
    float* bufB   = bufA + (size_t)N_NODES * F;         // [N_NODES, F]
    float* dinv   = bufB + (size_t)N_NODES * F;         // [N_NODES]
    int*   deg    = (int*)(dinv + N_NODES);             // [N_NODES]
    int*   cursor = deg + N_NODES;                      // [N_NODES]
    int*   row_ptr= cursor + N_NODES;                   // [N_NODES+1]
    int*   btot   = row_ptr + N_NODES + 1;              // [256]
    int*   srcs_s = btot + 256;                         // [N_EDGES]
    float* pooled = (float*)(srcs_s + N_EDGES);         // [64, 768]

    // ---- degree + norm + CSR ----
    hipMemsetAsync(deg, 0, 2 * N_NODES * sizeof(int), stream);   // deg + cursor
    count_deg<<<(N_EDGES + 255) / 256, 256, 0, stream>>>(dst, deg);
    compute_dinv<<<(N_NODES + 255) / 256, 256, 0, stream>>>(deg, dinv);
    scan_blocks<<<SCAN_NB, 256, 0, stream>>>(deg, row_ptr, btot);
    scan_totals<<<1, 256, 0, stream>>>(btot);
    add_offsets<<<SCAN_NB, 256, 0, stream>>>(row_ptr, btot);
    bucket_edges<<<(N_EDGES + 255) / 256, 256, 0, stream>>>(src, dst, row_ptr, cursor, srcs_s);

    dim3 ggrid(F / TN, (N_NODES + TM - 1) / TM);

    // ---- layer 1 ----
    gemm_fp32<<<ggrid, 256, 0, stream>>>(x, W1, bufA, N_NODES);
    gather_agg<<<N_NODES, 64, 0, stream>>>(row_ptr, srcs_s, dinv, bufA, b1, bufB);

    // ---- layer 2 ----
    gemm_fp32<<<ggrid, 256, 0, stream>>>(bufB, W2, bufA, N_NODES);
    gather_agg<<<N_NODES, 64, 0, stream>>>(row_ptr, srcs_s, dinv, bufA, b2, bufB);

    // ---- pooling + classifier ----
    pool_kernel<<<N_GRAPHS, 256, 0, stream>>>(bufB, batch, pooled);
    final_gemm<<<N_GRAPHS, F_OUT, 0, stream>>>(pooled, Wfc, bfc, out);
}

// Round 3
// 642.499 us; speedup vs baseline: 3.2844x; 1.5700x over previous
//
#include <hip/hip_runtime.h>

#define N_NODES 50000
#define N_EDGES 800000
#define N_GRAPHS 64
#define F 256        // F_IN == F_HID
#define F_OUT 128
#define G_DIM 768    // 3*F
#define SCAN_NB ((N_NODES + 255) / 256)   // 196
#define POOL_CHUNKS 16

typedef short short8 __attribute__((ext_vector_type(8)));
typedef short short4v __attribute__((ext_vector_type(4)));
typedef float float4v __attribute__((ext_vector_type(4)));

// ---- bf16 split helpers (RNE) ----
__device__ __forceinline__ unsigned short f2bf(float f) {
    unsigned int u = __float_as_uint(f);
    u += 0x7FFFu + ((u >> 16) & 1u);
    return (unsigned short)(u >> 16);
}
__device__ __forceinline__ float bf2f(unsigned short s) {
    return __uint_as_float(((unsigned int)s) << 16);
}

// ---------------- degree count (int) ----------------
__global__ void count_deg(const int* __restrict__ dst, int* deg) {
    int e = blockIdx.x * blockDim.x + threadIdx.x;
    if (e < N_EDGES) atomicAdd(&deg[dst[e]], 1);
}

__global__ void compute_dinv(const int* __restrict__ deg, float* dinv) {
    int i = blockIdx.x * blockDim.x + threadIdx.x;
    if (i < N_NODES) dinv[i] = rsqrtf((float)(deg[i] + 1));   // +1 self-loop
}

// ---------------- 3-kernel exclusive scan over deg -> row_ptr ----------------
__global__ void scan_blocks(const int* __restrict__ deg, int* __restrict__ row_ptr,
                            int* __restrict__ block_tot) {
    __shared__ int sd[256];
    int t = threadIdx.x;
    int idx = blockIdx.x * 256 + t;
    int v = (idx < N_NODES) ? deg[idx] : 0;
    sd[t] = v;
    __syncthreads();
    for (int off = 1; off < 256; off <<= 1) {
        int a = (t >= off) ? sd[t - off] : 0;
        __syncthreads();
        sd[t] += a;
        __syncthreads();
    }
    if (idx < N_NODES) row_ptr[idx] = sd[t] - v;
    if (t == 255) block_tot[blockIdx.x] = sd[255];
}

__global__ void scan_totals(int* block_tot) {
    __shared__ int sd[256];
    int t = threadIdx.x;
    int v = (t < SCAN_NB) ? block_tot[t] : 0;
    sd[t] = v;
    __syncthreads();
    for (int off = 1; off < 256; off <<= 1) {
        int a = (t >= off) ? sd[t - off] : 0;
        __syncthreads();
        sd[t] += a;
        __syncthreads();
    }
    if (t < SCAN_NB) block_tot[t] = sd[t] - v;
}

__global__ void add_offsets(int* __restrict__ row_ptr, const int* __restrict__ block_tot) {
    int idx = blockIdx.x * 256 + threadIdx.x;
    if (idx < N_NODES) row_ptr[idx] += block_tot[blockIdx.x];
    if (idx == 0) row_ptr[N_NODES] = N_EDGES;
}

// ---------------- bucket edges into CSR order ----------------
__global__ void bucket_edges(const int* __restrict__ src, const int* __restrict__ dst,
                             const int* __restrict__ row_ptr, int* __restrict__ cursor,
                             int* __restrict__ srcs_sorted) {
    int e = blockIdx.x * blockDim.x + threadIdx.x;
    if (e < N_EDGES) {
        int d = dst[e];
        int pos = atomicAdd(&cursor[d], 1);
        srcs_sorted[row_ptr[d] + pos] = src[e];
    }
}

// ---------------- casts ----------------
// x [N,256] fp32 -> hi/lo bf16 (flat, float4-vectorized)
__global__ void cast_split(const float* __restrict__ A, short* __restrict__ hi,
                           short* __restrict__ lo, int n4) {
    int i = blockIdx.x * blockDim.x + threadIdx.x;
    if (i < n4) {
        float4 v = ((const float4*)A)[i];
        short4v h, l;
        h.x = (short)f2bf(v.x); l.x = (short)f2bf(v.x - bf2f(h.x));
        h.y = (short)f2bf(v.y); l.y = (short)f2bf(v.y - bf2f(h.y));
        h.z = (short)f2bf(v.z); l.z = (short)f2bf(v.z - bf2f(h.z));
        h.w = (short)f2bf(v.w); l.w = (short)f2bf(v.w - bf2f(h.w));
        ((short4v*)hi)[i] = h;
        ((short4v*)lo)[i] = l;
    }
}

// W [256][256] -> transposed hi/lo: Bt[n][k] = W[k][n]
__global__ void cast_w_t(const float* __restrict__ W, short* __restrict__ hi,
                         short* __restrict__ lo) {
    int n = blockIdx.x;    // 256
    int k = threadIdx.x;   // 256
    float v = W[k * 256 + n];
    unsigned short h = f2bf(v);
    hi[n * 256 + k] = (short)h;
    lo[n * 256 + k] = (short)f2bf(v - bf2f(h));
}

// ---------------- split-bf16 MFMA GEMM ----------------
// C[M,256] = A[M,256] @ W[256,256], A given as hi/lo bf16 (row-major),
// W given as TRANSPOSED hi/lo bf16 (Bt[n][k]).  No LDS; frags straight from global.
// Block = 256 thr (4 waves), tile 128x128, wave tile 64x64.
__global__ __launch_bounds__(256) void gemm_mfma(
        const short* __restrict__ Ahi, const short* __restrict__ Alo,
        const short* __restrict__ Bthi, const short* __restrict__ Btlo,
        float* __restrict__ C, int M) {
    int wave = threadIdx.x >> 6;
    int lane = threadIdx.x & 63;
    int q = lane >> 4;       // k-chunk quad
    int t = lane & 15;       // row (A) / col (B,D)
    int row0 = blockIdx.y * 128 + (wave >> 1) * 64;
    int col0 = blockIdx.x * 128 + (wave & 1) * 64;

    float4v acc[4][4] = {};
    for (int kt = 0; kt < 256; kt += 32) {
        short8 ah[4], al[4], bh[4], bl[4];
#pragma unroll
        for (int mi = 0; mi < 4; ++mi) {
            int r = row0 + mi * 16 + t;
            if (r >= M) r = M - 1;            // clamp; OOB rows never stored
            size_t off = (size_t)r * 256 + kt + q * 8;
            ah[mi] = *(const short8*)&Ahi[off];
            al[mi] = *(const short8*)&Alo[off];
        }
#pragma unroll
        for (int ni = 0; ni < 4; ++ni) {
            int n = col0 + ni * 16 + t;
            size_t off = (size_t)n * 256 + kt + q * 8;
            bh[ni] = *(const short8*)&Bthi[off];
            bl[ni] = *(const short8*)&Btlo[off];
        }
#pragma unroll
        for (int mi = 0; mi < 4; ++mi)
#pragma unroll
            for (int ni = 0; ni < 4; ++ni) {
                acc[mi][ni] = __builtin_amdgcn_mfma_f32_16x16x32_bf16(ah[mi], bh[ni], acc[mi][ni], 0, 0, 0);
                acc[mi][ni] = __builtin_amdgcn_mfma_f32_16x16x32_bf16(ah[mi], bl[ni], acc[mi][ni], 0, 0, 0);
                acc[mi][ni] = __builtin_amdgcn_mfma_f32_16x16x32_bf16(al[mi], bh[ni], acc[mi][ni], 0, 0, 0);
            }
    }
    // D: row = q*4 + rr (within 16-tile), col = t
#pragma unroll
    for (int mi = 0; mi < 4; ++mi) {
        int gr0 = row0 + mi * 16 + q * 4;
#pragma unroll
        for (int rr = 0; rr < 4; ++rr) {
            int gr = gr0 + rr;
            if (gr < M) {
#pragma unroll
                for (int ni = 0; ni < 4; ++ni)
                    C[(size_t)gr * 256 + col0 + ni * 16 + t] = acc[mi][ni][rr];
            }
        }
    }
}

// -------- CSR gather-aggregate, fused self-loop + bias + relu --------
// BF16OUT: write bf16 hi/lo (feeds next gemm); else fp32 (feeds pooling)
template<bool BF16OUT>
__global__ __launch_bounds__(64) void gather_agg(
        const int* __restrict__ row_ptr, const int* __restrict__ srcs,
        const float* __restrict__ dinv, const float* __restrict__ hW,
        const float* __restrict__ b, float* __restrict__ outF,
        short* __restrict__ outHi, short* __restrict__ outLo) {
    int node = blockIdx.x;
    int lane = threadIdx.x;   // 64
    int beg = row_ptr[node], end = row_ptr[node + 1];
    float dd = dinv[node];
    const float4* hv = (const float4*)hW;
    float4 acc = make_float4(0.f, 0.f, 0.f, 0.f);
    for (int cbeg = beg; cbeg < end; cbeg += 64) {
        int n = end - cbeg; if (n > 64) n = 64;
        int sv = (lane < n) ? srcs[cbeg + lane] : 0;
        float wv = (lane < n) ? dinv[sv] : 0.f;
        for (int i = 0; i < n; ++i) {
            int s = __shfl(sv, i);
            float w = __shfl(wv, i) * dd;
            float4 v = hv[(size_t)s * 64 + lane];
            acc.x = fmaf(v.x, w, acc.x);
            acc.y = fmaf(v.y, w, acc.y);
            acc.z = fmaf(v.z, w, acc.z);
            acc.w = fmaf(v.w, w, acc.w);
        }
    }
    float4 sv4 = hv[(size_t)node * 64 + lane];
    float wself = dd * dd;
    float4 b4 = ((const float4*)b)[lane];
    acc.x = fmaxf(fmaf(sv4.x, wself, acc.x) + b4.x, 0.f);
    acc.y = fmaxf(fmaf(sv4.y, wself, acc.y) + b4.y, 0.f);
    acc.z = fmaxf(fmaf(sv4.z, wself, acc.z) + b4.z, 0.f);
    acc.w = fmaxf(fmaf(sv4.w, wself, acc.w) + b4.w, 0.f);
    if (BF16OUT) {
        short4v h, l;
        h.x = (short)f2bf(acc.x); l.x = (short)f2bf(acc.x - bf2f(h.x));
        h.y = (short)f2bf(acc.y); l.y = (short)f2bf(acc.y - bf2f(h.y));
        h.z = (short)f2bf(acc.z); l.z = (short)f2bf(acc.z - bf2f(h.z));
        h.w = (short)f2bf(acc.w); l.w = (short)f2bf(acc.w - bf2f(h.w));
        ((short4v*)outHi)[(size_t)node * 64 + lane] = h;
        ((short4v*)outLo)[(size_t)node * 64 + lane] = l;
    } else {
        ((float4*)outF)[(size_t)node * 64 + lane] = acc;
    }
}

// ---------------- parallel triple pooling ----------------
// grid (64, POOL_CHUNKS); partial sum/max -> atomics.  h >= 0 (post-relu), so
// int-compare atomicMax on float bits is order-correct and 0-init is identity.
__global__ void pool_partial(const float* __restrict__ h, const int* __restrict__ batch,
                             float* __restrict__ psum, int* __restrict__ pmaxi) {
    int g = blockIdx.x;
    int chunk = blockIdx.y;
    int f = threadIdx.x;  // 256
    __shared__ int s_start, s_end;
    if (threadIdx.x == 0) {
        int lo = 0, hi = N_NODES;
        while (lo < hi) { int mid = (lo + hi) >> 1; if (batch[mid] < g) lo = mid + 1; else hi = mid; }
        s_start = lo;
        lo = 0; hi = N_NODES;
        while (lo < hi) { int mid = (lo + hi) >> 1; if (batch[mid] < g + 1) lo = mid + 1; else hi = mid; }
        s_end = lo;
    }
    __syncthreads();
    int start = s_start, end = s_end;
    int len = end - start;
    if (len <= 0) return;
    int per = (len + POOL_CHUNKS - 1) / POOL_CHUNKS;
    int cs = start + chunk * per;
    int ce = cs + per; if (ce > end) ce = end;
    if (cs >= ce) return;
    float sum = 0.0f, mx = 0.0f;
    for (int n = cs; n < ce; ++n) {
        float v = h[(size_t)n * F + f];
        sum += v;
        mx = fmaxf(mx, v);
    }
    atomicAdd(&psum[g * F + f], sum);
    atomicMax(&pmaxi[g * F + f], __float_as_int(mx));
}

// ---------------- final GEMM: out[64,128] = [mean|max|sum] @ Wfc + bfc ----------------
__global__ void final_gemm(const float* __restrict__ psum, const int* __restrict__ pmaxi,
                           const int* __restrict__ batch,
                           const float* __restrict__ Wfc, const float* __restrict__ bfc,
                           float* __restrict__ out) {
    int g = blockIdx.x;   // 64
    int o = threadIdx.x;  // 128
    __shared__ float row[G_DIM];
    __shared__ int s_cnt;
    if (threadIdx.x == 0) {
        int lo = 0, hi = N_NODES;
        while (lo < hi) { int mid = (lo + hi) >> 1; if (batch[mid] < g) lo = mid + 1; else hi = mid; }
        int start = lo;
        lo = 0; hi = N_NODES;
        while (lo < hi) { int mid = (lo + hi) >> 1; if (batch[mid] < g + 1) lo = mid + 1; else hi = mid; }
        s_cnt = lo - start;
    }
    __syncthreads();
    float inv = 1.0f / fmaxf((float)s_cnt, 1.0f);
    for (int i = threadIdx.x; i < F; i += 128) {
        float s = psum[g * F + i];
        row[i]       = s * inv;
        row[F + i]   = __int_as_float(pmaxi[g * F + i]);
        row[2*F + i] = s;
    }
    __syncthreads();
    float acc = bfc[o];
    for (int k = 0; k < G_DIM; ++k) acc += row[k] * Wfc[k * F_OUT + o];
    out[g * F_OUT + o] = acc;
}

extern "C" void kernel_launch(void* const* d_in, const int* in_sizes, int n_in,
                              void* d_out, int out_size, void* d_ws, size_t ws_size,
                              hipStream_t stream) {
    const float* x    = (const float*)d_in[0];
    const int*   ei   = (const int*)d_in[1];
    const int*   batch= (const int*)d_in[2];
    const float* W1   = (const float*)d_in[4];
    const float* b1   = (const float*)d_in[5];
    const float* W2   = (const float*)d_in[6];
    const float* b2   = (const float*)d_in[7];
    const float* Wfc  = (const float*)d_in[8];
    const float* bfc  = (const float*)d_in[9];
    float* out = (float*)d_out;

    const int* src = ei;
    const int* dst = ei + N_EDGES;

    const size_t NF = (size_t)N_NODES * F;   // 12.8M

    float* bufA  = (float*)d_ws;             // [N,256] fp32 gemm out (51.2 MB)
    short* xhi   = (short*)(bufA + NF);      // [N,256] bf16 hi (25.6 MB) — reused as h1hi
    short* xlo   = xhi + NF;                 // lo (25.6 MB) — reused as h1lo
    float* h2    = (float*)xhi;              // alias: layer-2 fp32 out spans xhi+xlo
    short* w1hi  = xlo + NF;                 // 4x 64K shorts
    short* w1lo  = w1hi + 65536;
    short* w2hi  = w1lo + 65536;
    short* w2lo  = w2hi + 65536;
    float* dinv  = (float*)(w2lo + 65536);   // [N]
    int*   deg   = (int*)(dinv + N_NODES);   // [N]
    int*   cursor= deg + N_NODES;            // [N]
    int*   row_ptr = cursor + N_NODES;       // [N+1]
    int*   btot  = row_ptr + N_NODES + 1;    // [256]
    int*   srcs_s = btot + 256;              // [E]
    float* psum  = (float*)(srcs_s + N_EDGES);   // [64][256]
    int*   pmaxi = (int*)(psum + N_GRAPHS * F);  // [64][256]

    // ---- degree + norm + CSR ----
    hipMemsetAsync(deg, 0, 2 * N_NODES * sizeof(int), stream);   // deg + cursor
    count_deg<<<(N_EDGES + 255) / 256, 256, 0, stream>>>(dst, deg);
    compute_dinv<<<(N_NODES + 255) / 256, 256, 0, stream>>>(deg, dinv);
    scan_blocks<<<SCAN_NB, 256, 0, stream>>>(deg, row_ptr, btot);
    scan_totals<<<1, 256, 0, stream>>>(btot);
    add_offsets<<<SCAN_NB, 256, 0, stream>>>(row_ptr, btot);
    bucket_edges<<<(N_EDGES + 255) / 256, 256, 0, stream>>>(src, dst, row_ptr, cursor, srcs_s);

    // ---- casts ----
    cast_split<<<(NF / 4 + 255) / 256, 256, 0, stream>>>(x, xhi, xlo, NF / 4);
    cast_w_t<<<256, 256, 0, stream>>>(W1, w1hi, w1lo);
    cast_w_t<<<256, 256, 0, stream>>>(W2, w2hi, w2lo);

    dim3 ggrid(2, (N_NODES + 127) / 128);   // (2, 391)

    // ---- layer 1 ----
    gemm_mfma<<<ggrid, 256, 0, stream>>>(xhi, xlo, w1hi, w1lo, bufA, N_NODES);
    gather_agg<true><<<N_NODES, 64, 0, stream>>>(row_ptr, srcs_s, dinv, bufA, b1,
                                                 nullptr, xhi, xlo);  // h1 -> bf16 hi/lo

    // ---- layer 2 ----
    gemm_mfma<<<ggrid, 256, 0, stream>>>(xhi, xlo, w2hi, w2lo, bufA, N_NODES);
    gather_agg<false><<<N_NODES, 64, 0, stream>>>(row_ptr, srcs_s, dinv, bufA, b2,
                                                  h2, nullptr, nullptr);  // h2 fp32

    // ---- pooling + classifier ----
    hipMemsetAsync(psum, 0, N_GRAPHS * F * 2 * sizeof(float), stream);   // psum + pmaxi
    pool_partial<<<dim3(N_GRAPHS, POOL_CHUNKS), 256, 0, stream>>>(h2, batch, psum, pmaxi);
    final_gemm<<<N_GRAPHS, F_OUT, 0, stream>>>(psum, pmaxi, batch, Wfc, bfc, out);
}

// Round 4
// 584.064 us; speedup vs baseline: 3.6130x; 1.1001x over previous
//
#include <hip/hip_runtime.h>

#define N_NODES 50000
#define N_EDGES 800000
#define N_GRAPHS 64
#define F 256        // F_IN == F_HID
#define F_OUT 128
#define G_DIM 768    // 3*F
#define SCAN_NB ((N_NODES + 255) / 256)   // 196
#define POOL_CHUNKS 16

typedef short short8 __attribute__((ext_vector_type(8)));
typedef short short4v __attribute__((ext_vector_type(4)));
typedef float float4v __attribute__((ext_vector_type(4)));

// ---- bf16 split helpers (RNE) ----
__device__ __forceinline__ unsigned short f2bf(float f) {
    unsigned int u = __float_as_uint(f);
    u += 0x7FFFu + ((u >> 16) & 1u);
    return (unsigned short)(u >> 16);
}
__device__ __forceinline__ float bf2f(unsigned short s) {
    return __uint_as_float(((unsigned int)s) << 16);
}

// ---- async global->LDS, 16B per lane; LDS dest = uniform base + lane*16 ----
__device__ __forceinline__ void gld_lds16(const void* gsrc, void* ldst) {
    __builtin_amdgcn_global_load_lds(
        (const __attribute__((address_space(1))) unsigned int*)gsrc,
        (__attribute__((address_space(3))) unsigned int*)ldst, 16, 0, 0);
}

// ---------------- degree count (int) ----------------
__global__ void count_deg(const int* __restrict__ dst, int* deg) {
    int e = blockIdx.x * blockDim.x + threadIdx.x;
    if (e < N_EDGES) atomicAdd(&deg[dst[e]], 1);
}

__global__ void compute_dinv(const int* __restrict__ deg, float* dinv) {
    int i = blockIdx.x * blockDim.x + threadIdx.x;
    if (i < N_NODES) dinv[i] = rsqrtf((float)(deg[i] + 1));   // +1 self-loop
}

// ---------------- 3-kernel exclusive scan over deg -> row_ptr ----------------
__global__ void scan_blocks(const int* __restrict__ deg, int* __restrict__ row_ptr,
                            int* __restrict__ block_tot) {
    __shared__ int sd[256];
    int t = threadIdx.x;
    int idx = blockIdx.x * 256 + t;
    int v = (idx < N_NODES) ? deg[idx] : 0;
    sd[t] = v;
    __syncthreads();
    for (int off = 1; off < 256; off <<= 1) {
        int a = (t >= off) ? sd[t - off] : 0;
        __syncthreads();
        sd[t] += a;
        __syncthreads();
    }
    if (idx < N_NODES) row_ptr[idx] = sd[t] - v;
    if (t == 255) block_tot[blockIdx.x] = sd[255];
}

__global__ void scan_totals(int* block_tot) {
    __shared__ int sd[256];
    int t = threadIdx.x;
    int v = (t < SCAN_NB) ? block_tot[t] : 0;
    sd[t] = v;
    __syncthreads();
    for (int off = 1; off < 256; off <<= 1) {
        int a = (t >= off) ? sd[t - off] : 0;
        __syncthreads();
        sd[t] += a;
        __syncthreads();
    }
    if (t < SCAN_NB) block_tot[t] = sd[t] - v;
}

__global__ void add_offsets(int* __restrict__ row_ptr, const int* __restrict__ block_tot) {
    int idx = blockIdx.x * 256 + threadIdx.x;
    if (idx < N_NODES) row_ptr[idx] += block_tot[blockIdx.x];
    if (idx == 0) row_ptr[N_NODES] = N_EDGES;
}

// ---------------- bucket edges into CSR order ----------------
__global__ void bucket_edges(const int* __restrict__ src, const int* __restrict__ dst,
                             const int* __restrict__ row_ptr, int* __restrict__ cursor,
                             int* __restrict__ srcs_sorted) {
    int e = blockIdx.x * blockDim.x + threadIdx.x;
    if (e < N_EDGES) {
        int d = dst[e];
        int pos = atomicAdd(&cursor[d], 1);
        srcs_sorted[row_ptr[d] + pos] = src[e];
    }
}

// ---------------- casts ----------------
__global__ void cast_split(const float* __restrict__ A, short* __restrict__ hi,
                           short* __restrict__ lo, int n4) {
    int i = blockIdx.x * blockDim.x + threadIdx.x;
    if (i < n4) {
        float4 v = ((const float4*)A)[i];
        short4v h, l;
        h.x = (short)f2bf(v.x); l.x = (short)f2bf(v.x - bf2f(h.x));
        h.y = (short)f2bf(v.y); l.y = (short)f2bf(v.y - bf2f(h.y));
        h.z = (short)f2bf(v.z); l.z = (short)f2bf(v.z - bf2f(h.z));
        h.w = (short)f2bf(v.w); l.w = (short)f2bf(v.w - bf2f(h.w));
        ((short4v*)hi)[i] = h;
        ((short4v*)lo)[i] = l;
    }
}

// W [256][256] -> transposed hi/lo: Bt[n][k] = W[k][n]
__global__ void cast_w_t(const float* __restrict__ W, short* __restrict__ hi,
                         short* __restrict__ lo) {
    int n = blockIdx.x;    // 256
    int k = threadIdx.x;   // 256
    float v = W[k * 256 + n];
    unsigned short h = f2bf(v);
    hi[n * 256 + k] = (short)h;
    lo[n * 256 + k] = (short)f2bf(v - bf2f(h));
}

// ---------------- split-bf16 MFMA GEMM with LDS staging (m97 structure) ----------------
// C[M,256] = A[M,256] @ W[256,256]; A as hi/lo bf16 row-major, W as transposed hi/lo.
// Block 256 thr (4 waves), tile 128x128, wave tile 64x64, BK=32.
#define BM 128
#define BN 128
#define BK 32
__global__ __launch_bounds__(256) void gemm_mfma(
        const short* __restrict__ Ahi, const short* __restrict__ Alo,
        const short* __restrict__ Bthi, const short* __restrict__ Btlo,
        float* __restrict__ C, int M) {
    __shared__ short sAh[BM * BK], sAl[BM * BK], sBh[BN * BK], sBl[BN * BK];
    int tid = threadIdx.x;
    int wave = tid >> 6, lane = tid & 63;
    int q = lane >> 4, t = lane & 15;
    int row0 = blockIdx.y * BM;
    int col0 = blockIdx.x * BN;
    int wr = (wave >> 1) * 64;
    int wc = (wave & 1) * 64;

    // staging: wave w stages rows w*32..w*32+31 of each array (2 instrs of 16 rows each)
    int lrow = lane >> 2;          // 0..15
    int lk = (lane & 3) * 8;       // k offset (shorts)
    int srow0 = wave * 32;

    float4v acc[4][4] = {};
    for (int kt = 0; kt < 256; kt += BK) {
#pragma unroll
        for (int half = 0; half < 2; ++half) {
            int r = srow0 + half * 16 + lrow;
            int ga = row0 + r; if (ga >= M) ga = M - 1;   // clamp; never stored
            size_t aoff = (size_t)ga * 256 + kt + lk;
            size_t boff = (size_t)(col0 + r) * 256 + kt + lk;
            int ldso = (srow0 + half * 16) * BK;
            gld_lds16(&Ahi[aoff], &sAh[ldso]);
            gld_lds16(&Alo[aoff], &sAl[ldso]);
            gld_lds16(&Bthi[boff], &sBh[ldso]);
            gld_lds16(&Btlo[boff], &sBl[ldso]);
        }
        __syncthreads();
        short8 ah[4], al[4], bh[4], bl[4];
#pragma unroll
        for (int mi = 0; mi < 4; ++mi) {
            int r = wr + mi * 16 + t;
            ah[mi] = *(const short8*)&sAh[r * BK + q * 8];
            al[mi] = *(const short8*)&sAl[r * BK + q * 8];
        }
#pragma unroll
        for (int ni = 0; ni < 4; ++ni) {
            int n = wc + ni * 16 + t;
            bh[ni] = *(const short8*)&sBh[n * BK + q * 8];
            bl[ni] = *(const short8*)&sBl[n * BK + q * 8];
        }
#pragma unroll
        for (int mi = 0; mi < 4; ++mi)
#pragma unroll
            for (int ni = 0; ni < 4; ++ni) {
                acc[mi][ni] = __builtin_amdgcn_mfma_f32_16x16x32_bf16(ah[mi], bh[ni], acc[mi][ni], 0, 0, 0);
                acc[mi][ni] = __builtin_amdgcn_mfma_f32_16x16x32_bf16(ah[mi], bl[ni], acc[mi][ni], 0, 0, 0);
                acc[mi][ni] = __builtin_amdgcn_mfma_f32_16x16x32_bf16(al[mi], bh[ni], acc[mi][ni], 0, 0, 0);
            }
        __syncthreads();
    }
    // D: row = q*4 + rr, col = t (within each 16x16 tile)
#pragma unroll
    for (int mi = 0; mi < 4; ++mi) {
        int gr0 = row0 + wr + mi * 16 + q * 4;
#pragma unroll
        for (int rr = 0; rr < 4; ++rr) {
            int gr = gr0 + rr;
            if (gr < M) {
#pragma unroll
                for (int ni = 0; ni < 4; ++ni)
                    C[(size_t)gr * 256 + col0 + wc + ni * 16 + t] = acc[mi][ni][rr];
            }
        }
    }
}

// -------- CSR gather-aggregate, fused self-loop + bias + relu, 4x unrolled --------
template<bool BF16OUT>
__global__ __launch_bounds__(64) void gather_agg(
        const int* __restrict__ row_ptr, const int* __restrict__ srcs,
        const float* __restrict__ dinv, const float* __restrict__ hW,
        const float* __restrict__ b, float* __restrict__ outF,
        short* __restrict__ outHi, short* __restrict__ outLo) {
    int node = blockIdx.x;
    int lane = threadIdx.x;   // 64
    int beg = row_ptr[node], end = row_ptr[node + 1];
    float dd = dinv[node];
    const float4* hv = (const float4*)hW;
    float4 acc = make_float4(0.f, 0.f, 0.f, 0.f);
    for (int cbeg = beg; cbeg < end; cbeg += 64) {
        int n = end - cbeg; if (n > 64) n = 64;
        int sv = (lane < n) ? srcs[cbeg + lane] : 0;
        float wv = (lane < n) ? dinv[sv] * dd : 0.f;
        int i = 0;
        for (; i + 4 <= n; i += 4) {
            int s0 = __shfl(sv, i),     s1 = __shfl(sv, i + 1);
            int s2 = __shfl(sv, i + 2), s3 = __shfl(sv, i + 3);
            float w0 = __shfl(wv, i),     w1 = __shfl(wv, i + 1);
            float w2 = __shfl(wv, i + 2), w3 = __shfl(wv, i + 3);
            float4 v0 = hv[(size_t)s0 * 64 + lane];
            float4 v1 = hv[(size_t)s1 * 64 + lane];
            float4 v2 = hv[(size_t)s2 * 64 + lane];
            float4 v3 = hv[(size_t)s3 * 64 + lane];
            acc.x = fmaf(v0.x, w0, acc.x); acc.y = fmaf(v0.y, w0, acc.y);
            acc.z = fmaf(v0.z, w0, acc.z); acc.w = fmaf(v0.w, w0, acc.w);
            acc.x = fmaf(v1.x, w1, acc.x); acc.y = fmaf(v1.y, w1, acc.y);
            acc.z = fmaf(v1.z, w1, acc.z); acc.w = fmaf(v1.w, w1, acc.w);
            acc.x = fmaf(v2.x, w2, acc.x); acc.y = fmaf(v2.y, w2, acc.y);
            acc.z = fmaf(v2.z, w2, acc.z); acc.w = fmaf(v2.w, w2, acc.w);
            acc.x = fmaf(v3.x, w3, acc.x); acc.y = fmaf(v3.y, w3, acc.y);
            acc.z = fmaf(v3.z, w3, acc.z); acc.w = fmaf(v3.w, w3, acc.w);
        }
        for (; i < n; ++i) {
            int s = __shfl(sv, i);
            float w = __shfl(wv, i);
            float4 v = hv[(size_t)s * 64 + lane];
            acc.x = fmaf(v.x, w, acc.x); acc.y = fmaf(v.y, w, acc.y);
            acc.z = fmaf(v.z, w, acc.z); acc.w = fmaf(v.w, w, acc.w);
        }
    }
    float4 sv4 = hv[(size_t)node * 64 + lane];
    float wself = dd * dd;
    float4 b4 = ((const float4*)b)[lane];
    acc.x = fmaxf(fmaf(sv4.x, wself, acc.x) + b4.x, 0.f);
    acc.y = fmaxf(fmaf(sv4.y, wself, acc.y) + b4.y, 0.f);
    acc.z = fmaxf(fmaf(sv4.z, wself, acc.z) + b4.z, 0.f);
    acc.w = fmaxf(fmaf(sv4.w, wself, acc.w) + b4.w, 0.f);
    if (BF16OUT) {
        short4v h, l;
        h.x = (short)f2bf(acc.x); l.x = (short)f2bf(acc.x - bf2f(h.x));
        h.y = (short)f2bf(acc.y); l.y = (short)f2bf(acc.y - bf2f(h.y));
        h.z = (short)f2bf(acc.z); l.z = (short)f2bf(acc.z - bf2f(h.z));
        h.w = (short)f2bf(acc.w); l.w = (short)f2bf(acc.w - bf2f(h.w));
        ((short4v*)outHi)[(size_t)node * 64 + lane] = h;
        ((short4v*)outLo)[(size_t)node * 64 + lane] = l;
    } else {
        ((float4*)outF)[(size_t)node * 64 + lane] = acc;
    }
}

// ---------------- parallel triple pooling (float4, 1 wave/block) ----------------
__global__ __launch_bounds__(64) void pool_partial(
        const float* __restrict__ h, const int* __restrict__ batch,
        float* __restrict__ psum, int* __restrict__ pmaxi) {
    int g = blockIdx.x;
    int chunk = blockIdx.y;
    int lane = threadIdx.x;  // 64; lane covers feats lane*4..lane*4+3
    int lo = 0, hi = N_NODES;
    while (lo < hi) { int mid = (lo + hi) >> 1; if (batch[mid] < g) lo = mid + 1; else hi = mid; }
    int start = lo;
    lo = 0; hi = N_NODES;
    while (lo < hi) { int mid = (lo + hi) >> 1; if (batch[mid] < g + 1) lo = mid + 1; else hi = mid; }
    int end = lo;
    int len = end - start;
    if (len <= 0) return;
    int per = (len + POOL_CHUNKS - 1) / POOL_CHUNKS;
    int cs = start + chunk * per;
    int ce = cs + per; if (ce > end) ce = end;
    if (cs >= ce) return;
    const float4* hv = (const float4*)h;
    float4 sum = make_float4(0.f, 0.f, 0.f, 0.f);
    float4 mx  = make_float4(0.f, 0.f, 0.f, 0.f);
    for (int n = cs; n < ce; ++n) {
        float4 v = hv[(size_t)n * 64 + lane];
        sum.x += v.x; sum.y += v.y; sum.z += v.z; sum.w += v.w;
        mx.x = fmaxf(mx.x, v.x); mx.y = fmaxf(mx.y, v.y);
        mx.z = fmaxf(mx.z, v.z); mx.w = fmaxf(mx.w, v.w);
    }
    float* ps = &psum[g * F + lane * 4];
    atomicAdd(&ps[0], sum.x); atomicAdd(&ps[1], sum.y);
    atomicAdd(&ps[2], sum.z); atomicAdd(&ps[3], sum.w);
    int* pm = &pmaxi[g * F + lane * 4];
    atomicMax(&pm[0], __float_as_int(mx.x)); atomicMax(&pm[1], __float_as_int(mx.y));
    atomicMax(&pm[2], __float_as_int(mx.z)); atomicMax(&pm[3], __float_as_int(mx.w));
}

// ---------------- final GEMM: out[64,128] = [mean|max|sum] @ Wfc + bfc ----------------
__global__ void final_gemm(const float* __restrict__ psum, const int* __restrict__ pmaxi,
                           const int* __restrict__ batch,
                           const float* __restrict__ Wfc, const float* __restrict__ bfc,
                           float* __restrict__ out) {
    int g = blockIdx.x;   // 64
    int o = threadIdx.x;  // 128
    __shared__ float row[G_DIM];
    __shared__ int s_cnt;
    if (threadIdx.x == 0) {
        int lo = 0, hi = N_NODES;
        while (lo < hi) { int mid = (lo + hi) >> 1; if (batch[mid] < g) lo = mid + 1; else hi = mid; }
        int start = lo;
        lo = 0; hi = N_NODES;
        while (lo < hi) { int mid = (lo + hi) >> 1; if (batch[mid] < g + 1) lo = mid + 1; else hi = mid; }
        s_cnt = lo - start;
    }
    __syncthreads();
    float inv = 1.0f / fmaxf((float)s_cnt, 1.0f);
    for (int i = threadIdx.x; i < F; i += 128) {
        float s = psum[g * F + i];
        row[i]       = s * inv;
        row[F + i]   = __int_as_float(pmaxi[g * F + i]);
        row[2*F + i] = s;
    }
    __syncthreads();
    float acc = bfc[o];
    for (int k = 0; k < G_DIM; ++k) acc += row[k] * Wfc[k * F_OUT + o];
    out[g * F_OUT + o] = acc;
}

extern "C" void kernel_launch(void* const* d_in, const int* in_sizes, int n_in,
                              void* d_out, int out_size, void* d_ws, size_t ws_size,
                              hipStream_t stream) {
    const float* x    = (const float*)d_in[0];
    const int*   ei   = (const int*)d_in[1];
    const int*   batch= (const int*)d_in[2];
    const float* W1   = (const float*)d_in[4];
    const float* b1   = (const float*)d_in[5];
    const float* W2   = (const float*)d_in[6];
    const float* b2   = (const float*)d_in[7];
    const float* Wfc  = (const float*)d_in[8];
    const float* bfc  = (const float*)d_in[9];
    float* out = (float*)d_out;

    const int* src = ei;
    const int* dst = ei + N_EDGES;

    const size_t NF = (size_t)N_NODES * F;   // 12.8M

    float* bufA  = (float*)d_ws;             // [N,256] fp32 gemm out (51.2 MB)
    short* xhi   = (short*)(bufA + NF);      // [N,256] bf16 hi — reused as h1hi
    short* xlo   = xhi + NF;                 // lo — reused as h1lo
    float* h2    = (float*)xhi;              // alias: layer-2 fp32 out spans xhi+xlo
    short* w1hi  = xlo + NF;
    short* w1lo  = w1hi + 65536;
    short* w2hi  = w1lo + 65536;
    short* w2lo  = w2hi + 65536;
    float* dinv  = (float*)(w2lo + 65536);
    int*   deg   = (int*)(dinv + N_NODES);
    int*   cursor= deg + N_NODES;
    int*   row_ptr = cursor + N_NODES;
    int*   btot  = row_ptr + N_NODES + 1;
    int*   srcs_s = btot + 256;
    float* psum  = (float*)(srcs_s + N_EDGES);   // [64][256]
    int*   pmaxi = (int*)(psum + N_GRAPHS * F);  // [64][256]

    // ---- degree + norm + CSR ----
    hipMemsetAsync(deg, 0, 2 * N_NODES * sizeof(int), stream);   // deg + cursor
    count_deg<<<(N_EDGES + 255) / 256, 256, 0, stream>>>(dst, deg);
    compute_dinv<<<(N_NODES + 255) / 256, 256, 0, stream>>>(deg, dinv);
    scan_blocks<<<SCAN_NB, 256, 0, stream>>>(deg, row_ptr, btot);
    scan_totals<<<1, 256, 0, stream>>>(btot);
    add_offsets<<<SCAN_NB, 256, 0, stream>>>(row_ptr, btot);
    bucket_edges<<<(N_EDGES + 255) / 256, 256, 0, stream>>>(src, dst, row_ptr, cursor, srcs_s);

    // ---- casts ----
    cast_split<<<(NF / 4 + 255) / 256, 256, 0, stream>>>(x, xhi, xlo, NF / 4);
    cast_w_t<<<256, 256, 0, stream>>>(W1, w1hi, w1lo);
    cast_w_t<<<256, 256, 0, stream>>>(W2, w2hi, w2lo);

    dim3 ggrid(2, (N_NODES + BM - 1) / BM);   // (2, 391)

    // ---- layer 1 ----
    gemm_mfma<<<ggrid, 256, 0, stream>>>(xhi, xlo, w1hi, w1lo, bufA, N_NODES);
    gather_agg<true><<<N_NODES, 64, 0, stream>>>(row_ptr, srcs_s, dinv, bufA, b1,
                                                 nullptr, xhi, xlo);

    // ---- layer 2 ----
    gemm_mfma<<<ggrid, 256, 0, stream>>>(xhi, xlo, w2hi, w2lo, bufA, N_NODES);
    gather_agg<false><<<N_NODES, 64, 0, stream>>>(row_ptr, srcs_s, dinv, bufA, b2,
                                                  h2, nullptr, nullptr);

    // ---- pooling + classifier ----
    hipMemsetAsync(psum, 0, N_GRAPHS * F * 2 * sizeof(float), stream);
    pool_partial<<<dim3(N_GRAPHS, POOL_CHUNKS), 64, 0, stream>>>(h2, batch, psum, pmaxi);
    final_gemm<<<N_GRAPHS, F_OUT, 0, stream>>>(psum, pmaxi, batch, Wfc, bfc, out);
}